// Round 14
// baseline (218.128 us; speedup 1.0000x reference)
//
#include <hip/hip_runtime.h>
#include <hip/hip_bf16.h>

#define BB 2
#define NN 2048
#define KVN 2048
#define CC 1024
#define HH 16
#define HD 64

typedef __bf16 bf16;
typedef __attribute__((ext_vector_type(4))) __bf16 bf16x4;
typedef __attribute__((ext_vector_type(8))) __bf16 bf16x8;
typedef __attribute__((ext_vector_type(4))) float f32x4;

__device__ __forceinline__ void gload_lds16(const void* g, void* l) {
  __builtin_amdgcn_global_load_lds(
      (const __attribute__((address_space(1))) void*)g,
      (__attribute__((address_space(3))) void*)l, 16, 0, 0);
}

__device__ __forceinline__ float exp2_raw(float x) {
  float r;
  asm("v_exp_f32 %0, %1" : "=v"(r) : "v"(x));   // D = 2^S0, 1 VALU op
  return r;
}

// ---------------- batched weight transpose: Wt[z][c][r] = (bf16)W_z[r][c]
__global__ __launch_bounds__(256)
void wtrans(const float* __restrict__ qW, const float* __restrict__ kW,
            const float* __restrict__ vW, const float* __restrict__ pW,
            bf16* __restrict__ Wt) {
  __shared__ bf16 t[64][72];
  const float* in = (blockIdx.z == 0) ? qW : (blockIdx.z == 1) ? kW
                    : (blockIdx.z == 2) ? vW : pW;
  bf16* out = Wt + (size_t)blockIdx.z * CC * CC;
  int r0 = blockIdx.y * 64, c0 = blockIdx.x * 64;
  int tid = threadIdx.x;
  int lr = tid >> 3, lc = (tid & 7) * 8;
  for (int p = 0; p < 2; ++p) {
    int rr = lr + p * 32;
    const float* src = &in[(size_t)(r0 + rr) * CC + c0 + lc];
    float4 a = *(const float4*)src;
    float4 b = *(const float4*)(src + 4);
    t[lc + 0][rr] = (bf16)a.x; t[lc + 1][rr] = (bf16)a.y;
    t[lc + 2][rr] = (bf16)a.z; t[lc + 3][rr] = (bf16)a.w;
    t[lc + 4][rr] = (bf16)b.x; t[lc + 5][rr] = (bf16)b.y;
    t[lc + 6][rr] = (bf16)b.z; t[lc + 7][rr] = (bf16)b.w;
  }
  __syncthreads();
  for (int p = 0; p < 2; ++p) {
    int rr = lr + p * 32;
    *(bf16x8*)&out[(size_t)(c0 + rr) * CC + r0 + lc] = *(const bf16x8*)&t[rr][lc];
  }
}

// ---------------- qkv fp32 -> bf16 prepass: Abf[z][row][col], 36 MB HBM (~6us)
__global__ __launch_bounds__(256)
void cvt_qkv(const float* __restrict__ qin, const float* __restrict__ kin,
             const float* __restrict__ vin, bf16* __restrict__ Abf) {
  const int z = blockIdx.y;
  const float* s = (z == 0) ? qin : (z == 1) ? kin : vin;
  size_t off = ((size_t)blockIdx.x * 256 + threadIdx.x) * 8;  // < 4194304
  float4 a = *(const float4*)(s + off);
  float4 b = *(const float4*)(s + off + 4);
  bf16x8 t;
  t[0] = (bf16)a.x; t[1] = (bf16)a.y; t[2] = (bf16)a.z; t[3] = (bf16)a.w;
  t[4] = (bf16)b.x; t[5] = (bf16)b.y; t[6] = (bf16)b.z; t[7] = (bf16)b.w;
  *(bf16x8*)&Abf[(size_t)z * ((size_t)BB * NN * CC) + off] = t;
}

// ---------------- merged QKV GEMM: 128x128 tile, BK=64 (round-8 v8 core).
// v9: kpack FUSED into the z==1 epilogue -- K (post-RoPE) is written directly
// in MFMA-A-frag order to Kpack, eliminating the kpack kernel's 16 MB
// round-trip. Address map (verified vs kpack_kernel's read indexing):
//   addr(key,d) = ((bh*32+tix)*8 + ((key>>4)&3)*2 + (d>>5))*512
//               + ((d>>3)&3)*128 + (key&15)*8 + (d&7)
// Store pattern per quad-group: 8 lanes -> 8 consecutive bf16 (16B segment),
// same scalar-store count as the old row write. z==0 folds log2(e) into the
// scale so attn3's softmax runs on raw v_exp_f32.
__global__ __launch_bounds__(256, 3)
void gemm_qkv(const bf16* __restrict__ Abf, const bf16* __restrict__ Wt,
              const float* __restrict__ pos, bf16* __restrict__ Qp,
              bf16* __restrict__ Kpack, bf16* __restrict__ Vp) {
  __shared__ bf16 As[128 * 64];   // 16 KB, chunks of 8: L = r*8 + (c^(r&7))
  __shared__ bf16 Bs[128 * 64];   // 16 KB, same swizzle
  const int bid = blockIdx.x;
  const int u = bid & 7, s = bid >> 3;       // s in [0,96)
  const int nblk = s >> 2;                   // 0..23
  const int m0 = (u * 4 + (s & 3)) * 128;
  const int z = nblk >> 3;
  const int n0 = (nblk & 7) * 128;
  const bf16* A = Abf + (size_t)z * ((size_t)BB * NN * CC);
  const bf16* Bt = Wt + (size_t)z * CC * CC;
  const int tid = threadIdx.x;
  const int wave = tid >> 6, lane = tid & 63;
  const int quad = lane >> 4, l15 = lane & 15;
  const int waveM = (wave >> 1) * 64, waveN = (wave & 1) * 64;
  f32x4 acc[4][4] = {};

  for (int k0 = 0; k0 < CC; k0 += 64) {
#pragma unroll
    for (int p = 0; p < 4; ++p) {   // B: 1024 bf16-chunks, async direct-to-LDS
      int ch = p * 256 + tid;
      int r = ch >> 3, c = (ch & 7) ^ (r & 7);
      gload_lds16(Bt + (size_t)(n0 + r) * CC + k0 + c * 8, &Bs[ch * 8]);
    }
#pragma unroll
    for (int p = 0; p < 4; ++p) {   // A: same proven path, bf16
      int ch = p * 256 + tid;
      int r = ch >> 3, c = (ch & 7) ^ (r & 7);
      gload_lds16(A + (size_t)(m0 + r) * CC + k0 + c * 8, &As[ch * 8]);
    }
    __syncthreads();
    bf16x8 af[4][2], bfr[4][2];
#pragma unroll
    for (int i = 0; i < 4; ++i) {
      int rA = waveM + i * 16 + l15;
      af[i][0] = *(const bf16x8*)&As[(rA * 8 + (quad ^ (rA & 7))) * 8];
      af[i][1] = *(const bf16x8*)&As[(rA * 8 + ((quad + 4) ^ (rA & 7))) * 8];
      int rB = waveN + i * 16 + l15;
      bfr[i][0] = *(const bf16x8*)&Bs[(rB * 8 + (quad ^ (rB & 7))) * 8];
      bfr[i][1] = *(const bf16x8*)&Bs[(rB * 8 + ((quad + 4) ^ (rB & 7))) * 8];
    }
#pragma unroll
    for (int mi = 0; mi < 4; ++mi)
#pragma unroll
      for (int ni = 0; ni < 4; ++ni) {
        acc[mi][ni] = __builtin_amdgcn_mfma_f32_16x16x32_bf16(
            af[mi][0], bfr[ni][0], acc[mi][ni], 0, 0, 0);
        acc[mi][ni] = __builtin_amdgcn_mfma_f32_16x16x32_bf16(
            af[mi][1], bfr[ni][1], acc[mi][ni], 0, 0, 0);
      }
    __syncthreads();
  }
  // epilogue: C/D col=lane&15, row=quad*4+reg; RoPE in-register for z<2.
  // z==0: scale = hd^-0.5 * log2(e) so attn3's softmax runs in base 2.
  const float scale = (z == 0) ? 0.125f * 1.44269504f : 1.0f;
  const int h2 = (n0 + waveN) >> 6;          // head for this wave's column group
#pragma unroll
  for (int mi = 0; mi < 4; ++mi) {
#pragma unroll
    for (int r = 0; r < 4; ++r) {
      int m = m0 + waveM + mi * 16 + quad * 4 + r;
      int l = m & (NN - 1);
      if (z == 2) {
#pragma unroll
        for (int ni = 0; ni < 4; ++ni)
          Vp[(size_t)m * CC + n0 + waveN + ni * 16 + l15] = (bf16)acc[mi][ni][r];
      } else if (z == 0) {
#pragma unroll
        for (int ni = 0; ni < 2; ++ni) {
          int col = n0 + waveN + ni * 16 + l15;
          int d = ni * 16 + l15;                 // head-local, in [0,32)
          float x1 = acc[mi][ni][r], x2 = acc[mi][ni + 2][r];
          float s1, c1, s2f, c2f;
          __sincosf(pos[l * HD + d], &s1, &c1);
          __sincosf(pos[l * HD + d + 32], &s2f, &c2f);
          Qp[(size_t)m * CC + col]      = (bf16)((x1 * c1 - x2 * s1) * scale);
          Qp[(size_t)m * CC + col + 32] = (bf16)((x2 * c2f + x1 * s2f) * scale);
        }
      } else {  // z == 1: RoPE + direct Kpack scatter (kpack kernel fused away)
        int key = l;                             // m & (NN-1)
        int bb2 = m >> 11;
        size_t kb_ = ((((size_t)(bb2 * HH + h2)) * 32 + (key >> 6)) * 8
                      + ((key >> 4) & 3) * 2) * 512 + (size_t)(key & 15) * 8;
#pragma unroll
        for (int ni = 0; ni < 2; ++ni) {
          int d = ni * 16 + l15;                 // in [0,32); pair at d+32
          float x1 = acc[mi][ni][r], x2 = acc[mi][ni + 2][r];
          float s1, c1, s2f, c2f;
          __sincosf(pos[l * HD + d], &s1, &c1);
          __sincosf(pos[l * HD + d + 32], &s2f, &c2f);
          size_t off = kb_ + ((d >> 3) & 3) * 128 + (d & 7);
          Kpack[off]       = (bf16)(x1 * c1 - x2 * s1);    // d
          Kpack[off + 512] = (bf16)(x2 * c2f + x1 * s2f);  // d+32 (hf=1)
        }
      }
    }
  }
}

// ---------------- V pack: V^T in A-frag order, pre-masked, + mask row (d=64).
__global__ __launch_bounds__(256)
void vpack_kernel(const bf16* __restrict__ Vp, const int* __restrict__ mask,
                  bf16* __restrict__ VpA, bf16* __restrict__ VpB) {
  __shared__ bf16 t[64][80];
  int tix = blockIdx.x, h = blockIdx.y, b = blockIdx.z;
  int j0 = tix * 64, bh = b * HH + h;
  const int* maskb = mask + b * KVN;
  int tid = threadIdx.x;
  int lr = tid >> 3, lc = (tid & 7) * 8;
  for (int p = 0; p < 2; ++p) {
    int j = lr + p * 32;
    int mv = maskb[j0 + j];
    bf16x8 v = *(const bf16x8*)&Vp[(size_t)(b * KVN + j0 + j) * CC + h * HD + lc];
#pragma unroll
    for (int uu = 0; uu < 8; ++uu) t[lc + uu][j] = mv ? v[uu] : (bf16)0.f;
  }
  __syncthreads();
  for (int p = 0; p < 3; ++p) {
    int sp = p * 256 + tid;
    if (sp < 640) {
      int fs = sp >> 6, lane = sp & 63, quad = (sp >> 4) & 3, l15 = sp & 15;
      int ni = fs >> 1, hf = fs & 1;
      bf16x8 v;
      if (ni < 4) {
        v = *(const bf16x8*)&t[ni * 16 + l15][hf * 32 + quad * 8];
      } else {
#pragma unroll
        for (int jj = 0; jj < 8; ++jj)
          v[jj] = (l15 == 0) ? (bf16)(float)maskb[j0 + hf * 32 + quad * 8 + jj]
                             : (bf16)0.f;
      }
      bf16* dst = (fs < 6) ? (VpA + (size_t)fs * (1 << 19))
                           : (VpB + (size_t)(fs - 6) * (1 << 19));
      *(bf16x8*)&dst[((size_t)(bh * 32 + tix)) * 512 + lane * 8] = v;
    }
  }
}

// ---------------- attention v7 (round-13 best measured 47.0us): grid 512,
// 2qc x 2kh waves, 16 iters, single parallel merge, base-2 softmax via raw
// v_exp_f32 (Q pre-scaled by log2e), setprio on MFMA clusters.
__global__ __launch_bounds__(256, 2)
void attn3(const bf16* __restrict__ Qp, const bf16* __restrict__ Kpack,
           const bf16* __restrict__ VpA, const bf16* __restrict__ VpB,
           bf16* __restrict__ X) {
  __shared__ char smem[49152];      // [0,8K): per-wave P; [8K,48K): merge buffer
  const int tid = threadIdx.x, wave = tid >> 6, lane = tid & 63;
  const int quad = lane >> 4, l15 = lane & 15;
  const int bid = blockIdx.x;
  const int u = bid & 7, s = bid >> 3;
  const int bh = u * 4 + (s & 3), qp = s >> 2;
  const int b = bh >> 4, h = bh & 15;
  const int qc = qp * 2 + (wave >> 1), kh = wave & 1;
  const int q0 = qc * 64;
  const int sw = 2 * (l15 & 7);

  bf16* P = (bf16*)(smem + wave * 2048);
  float* mrg = (float*)(smem + 8192);

  bf16x8 qa[4][2];
#pragma unroll
  for (int g = 0; g < 4; ++g) {
    const bf16* qrow = Qp + ((size_t)(b * NN) + q0 + g * 16 + l15) * CC + h * HD;
    qa[g][0] = *(const bf16x8*)&qrow[quad * 8];
    qa[g][1] = *(const bf16x8*)&qrow[32 + quad * 8];
  }

  f32x4 Oacc[4][5] = {};
  const bf16* kbase = Kpack + (size_t)bh * 32 * 8 * 512;

  for (int it = 0; it < 16; ++it) {
    int t = kh * 16 + it;
    bf16x8 kb[8], vb[10];
#pragma unroll
    for (int fs = 0; fs < 8; ++fs)
      kb[fs] = *(const bf16x8*)&kbase[((size_t)t * 8 + fs) * 512 + lane * 8];
#pragma unroll
    for (int fs = 0; fs < 10; ++fs) {
      const bf16* vbs = (fs < 6) ? (VpA + (size_t)fs * (1 << 19))
                                 : (VpB + (size_t)(fs - 6) * (1 << 19));
      vb[fs] = *(const bf16x8*)&vbs[((size_t)(bh * 32 + t)) * 512 + lane * 8];
    }
#pragma unroll
    for (int g = 0; g < 4; ++g) {
      f32x4 sg[4];
      __builtin_amdgcn_s_setprio(1);
#pragma unroll
      for (int ni = 0; ni < 4; ++ni) {
        f32x4 zz = {};
        zz = __builtin_amdgcn_mfma_f32_16x16x32_bf16(kb[ni * 2], qa[g][0], zz, 0, 0, 0);
        zz = __builtin_amdgcn_mfma_f32_16x16x32_bf16(kb[ni * 2 + 1], qa[g][1], zz, 0, 0, 0);
        sg[ni] = zz;
      }
      __builtin_amdgcn_s_setprio(0);
#pragma unroll
      for (int ni = 0; ni < 4; ++ni) {
        bf16x4 pk;
#pragma unroll
        for (int r = 0; r < 4; ++r) pk[r] = (bf16)exp2_raw(sg[ni][r] - 5.7707802f);
        *(bf16x4*)&P[(l15 * 16 + ((ni * 4 + quad) ^ sw)) * 4] = pk;
      }
      bf16x8 pf0 = *(const bf16x8*)&P[(l15 * 16 + ((quad * 2) ^ sw)) * 4];
      bf16x8 pf1 = *(const bf16x8*)&P[(l15 * 16 + ((8 + quad * 2) ^ sw)) * 4];
      __builtin_amdgcn_s_setprio(1);
#pragma unroll
      for (int ni = 0; ni < 5; ++ni) {
        Oacc[g][ni] = __builtin_amdgcn_mfma_f32_16x16x32_bf16(vb[ni * 2], pf0, Oacc[g][ni], 0, 0, 0);
        Oacc[g][ni] = __builtin_amdgcn_mfma_f32_16x16x32_bf16(vb[ni * 2 + 1], pf1, Oacc[g][ni], 0, 0, 0);
      }
      __builtin_amdgcn_s_setprio(0);
    }
  }
  if (kh == 1) {
    float* dst = mrg + (wave >> 1) * 5120 + lane * 4;
#pragma unroll
    for (int g = 0; g < 4; ++g)
#pragma unroll
      for (int ni = 0; ni < 5; ++ni)
        *(f32x4*)&dst[(g * 5 + ni) * 256] = Oacc[g][ni];
  }
  __syncthreads();
  if (kh == 0) {
    float* src = mrg + (wave >> 1) * 5120 + lane * 4;
#pragma unroll
    for (int g = 0; g < 4; ++g) {
#pragma unroll
      for (int ni = 0; ni < 5; ++ni) {
        f32x4 o = *(const f32x4*)&src[(g * 5 + ni) * 256];
#pragma unroll
        for (int r = 0; r < 4; ++r) Oacc[g][ni][r] += o[r];
      }
      float ls = __shfl(Oacc[g][4][0], l15, 64);
      float rn = 1.0f / ls;
#pragma unroll
      for (int ni = 0; ni < 4; ++ni) {
        bf16x4 ov;
#pragma unroll
        for (int r = 0; r < 4; ++r) ov[r] = (bf16)(Oacc[g][ni][r] * rn);
        *(bf16x4*)&X[((size_t)(b * NN) + q0 + g * 16 + l15) * CC
                     + h * HD + ni * 16 + quad * 4] = ov;
      }
    }
  }
}

// ---------------- projection GEMM: 64x128 tile, BK=64, 8-slot swizzle, grid 512
__global__ __launch_bounds__(256, 4)
void gemm_proj(const bf16* __restrict__ A, const bf16* __restrict__ Bt,
               float* __restrict__ Out) {
  __shared__ bf16 As[64 * 64];    // 8 KB
  __shared__ bf16 Bs[128 * 64];   // 16 KB
  const int bid = blockIdx.x;
  const int u = bid & 7, s = bid >> 3;        // s in [0,64)
  const int m0 = (u * 8 + (s >> 3)) * 64;
  const int n0 = (s & 7) * 128;
  const int tid = threadIdx.x;
  const int wave = tid >> 6, lane = tid & 63;
  const int quad = lane >> 4, l15 = lane & 15;
  const int waveM = (wave >> 1) * 32, waveN = (wave & 1) * 64;
  f32x4 acc[2][4] = {};

  for (int k0 = 0; k0 < CC; k0 += 64) {
#pragma unroll
    for (int p = 0; p < 2; ++p) {
      int ch = p * 256 + tid;
      int r = ch >> 3, c = (ch & 7) ^ (r & 7);
      gload_lds16(A + (size_t)(m0 + r) * CC + k0 + c * 8, &As[ch * 8]);
    }
#pragma unroll
    for (int p = 0; p < 4; ++p) {
      int ch = p * 256 + tid;
      int r = ch >> 3, c = (ch & 7) ^ (r & 7);
      gload_lds16(Bt + (size_t)(n0 + r) * CC + k0 + c * 8, &Bs[ch * 8]);
    }
    __syncthreads();
    bf16x8 af[2][2], bfr[4][2];
#pragma unroll
    for (int i = 0; i < 2; ++i) {
      int rA = waveM + i * 16 + l15;
      af[i][0] = *(const bf16x8*)&As[(rA * 8 + (quad ^ (rA & 7))) * 8];
      af[i][1] = *(const bf16x8*)&As[(rA * 8 + ((quad + 4) ^ (rA & 7))) * 8];
    }
#pragma unroll
    for (int i = 0; i < 4; ++i) {
      int rB = waveN + i * 16 + l15;
      bfr[i][0] = *(const bf16x8*)&Bs[(rB * 8 + (quad ^ (rB & 7))) * 8];
      bfr[i][1] = *(const bf16x8*)&Bs[(rB * 8 + ((quad + 4) ^ (rB & 7))) * 8];
    }
#pragma unroll
    for (int mi = 0; mi < 2; ++mi)
#pragma unroll
      for (int ni = 0; ni < 4; ++ni) {
        acc[mi][ni] = __builtin_amdgcn_mfma_f32_16x16x32_bf16(
            af[mi][0], bfr[ni][0], acc[mi][ni], 0, 0, 0);
        acc[mi][ni] = __builtin_amdgcn_mfma_f32_16x16x32_bf16(
            af[mi][1], bfr[ni][1], acc[mi][ni], 0, 0, 0);
      }
    __syncthreads();
  }
#pragma unroll
  for (int mi = 0; mi < 2; ++mi)
#pragma unroll
    for (int ni = 0; ni < 4; ++ni)
#pragma unroll
      for (int r = 0; r < 4; ++r) {
        int row = m0 + waveM + mi * 16 + quad * 4 + r;
        int col = n0 + waveN + ni * 16 + l15;
        Out[(size_t)row * CC + col] = acc[mi][ni][r];
      }
}

extern "C" void kernel_launch(void* const* d_in, const int* in_sizes, int n_in,
                              void* d_out, int out_size, void* d_ws, size_t ws_size,
                              hipStream_t stream) {
  const float* q    = (const float*)d_in[0];
  const float* k    = (const float*)d_in[1];
  const float* v    = (const float*)d_in[2];
  const int*   mask = (const int*)d_in[3];
  const float* pos  = (const float*)d_in[4];
  const float* qW   = (const float*)d_in[5];
  const float* kW   = (const float*)d_in[6];
  const float* vW   = (const float*)d_in[7];
  const float* pW   = (const float*)d_in[8];
  float* out = (float*)d_out;

  char* w = (char*)d_ws;
  const size_t MB = 1024 * 1024;
  // layout (<=44MB), kpack fused into gemm_qkv:
  //   Wt@0-8    (qWt/kWt/vWt dead after gemm_qkv; pWt@6-8 live to gemm_proj)
  //   Qp@8-16   (gemm_qkv -> attn3)
  //   Kpack@16-24 (WRITTEN by gemm_qkv -> attn3; former Kp slot)
  //   Vp@24-32  (gemm_qkv -> vpack)
  //   Abf@32-44 (cvt_qkv -> gemm_qkv, dead after)
  //   VpA@0-6   over dead qWt/kWt/vWt (vpack -> attn3)
  //   VpB@40-44 over dead Abf tail    (vpack -> attn3)
  //   X@32-40   over dead Abf head    (attn3 -> gemm_proj; no overlap w/ VpB)
  bf16* Wt    = (bf16*)(w);
  bf16* Qp    = (bf16*)(w + 8 * MB);
  bf16* Kpack = (bf16*)(w + 16 * MB);
  bf16* Vp    = (bf16*)(w + 24 * MB);
  bf16* Abf   = (bf16*)(w + 32 * MB);   // 12 MB, live only through gemm_qkv
  bf16* VpA   = (bf16*)(w);             // 6 MB over dead qWt/kWt/vWt
  bf16* VpB   = (bf16*)(w + 40 * MB);   // 4 MB over dead Abf tail
  bf16* X     = (bf16*)(w + 32 * MB);   // 8 MB over dead Abf head

  wtrans<<<dim3(16, 16, 4), 256, 0, stream>>>(qW, kW, vW, pW, Wt);
  cvt_qkv<<<dim3(2048, 3), 256, 0, stream>>>(q, k, v, Abf);
  gemm_qkv<<<dim3(768), 256, 0, stream>>>(Abf, Wt, pos, Qp, Kpack, Vp);
  vpack_kernel<<<dim3(KVN / 64, HH, BB), 256, 0, stream>>>(Vp, mask, VpA, VpB);
  attn3<<<dim3(512), 256, 0, stream>>>(Qp, Kpack, VpA, VpB, X);
  gemm_proj<<<dim3(512), 256, 0, stream>>>(X, Wt + 3 * (size_t)CC * CC, out);
}

// Round 15
// 208.510 us; speedup vs baseline: 1.0461x; 1.0461x over previous
//
#include <hip/hip_runtime.h>
#include <hip/hip_bf16.h>

#define BB 2
#define NN 2048
#define KVN 2048
#define CC 1024
#define HH 16
#define HD 64

typedef __bf16 bf16;
typedef __attribute__((ext_vector_type(4))) __bf16 bf16x4;
typedef __attribute__((ext_vector_type(8))) __bf16 bf16x8;
typedef __attribute__((ext_vector_type(4))) float f32x4;

__device__ __forceinline__ void gload_lds16(const void* g, void* l) {
  __builtin_amdgcn_global_load_lds(
      (const __attribute__((address_space(1))) void*)g,
      (__attribute__((address_space(3))) void*)l, 16, 0, 0);
}

__device__ __forceinline__ float exp2_raw(float x) {
  float r;
  asm("v_exp_f32 %0, %1" : "=v"(r) : "v"(x));   // D = 2^S0, 1 VALU op
  return r;
}

// ---------------- batched weight transpose: Wt[z][c][r] = (bf16)W_z[r][c]
__global__ __launch_bounds__(256)
void wtrans(const float* __restrict__ qW, const float* __restrict__ kW,
            const float* __restrict__ vW, const float* __restrict__ pW,
            bf16* __restrict__ Wt) {
  __shared__ bf16 t[64][72];
  const float* in = (blockIdx.z == 0) ? qW : (blockIdx.z == 1) ? kW
                    : (blockIdx.z == 2) ? vW : pW;
  bf16* out = Wt + (size_t)blockIdx.z * CC * CC;
  int r0 = blockIdx.y * 64, c0 = blockIdx.x * 64;
  int tid = threadIdx.x;
  int lr = tid >> 3, lc = (tid & 7) * 8;
  for (int p = 0; p < 2; ++p) {
    int rr = lr + p * 32;
    const float* src = &in[(size_t)(r0 + rr) * CC + c0 + lc];
    float4 a = *(const float4*)src;
    float4 b = *(const float4*)(src + 4);
    t[lc + 0][rr] = (bf16)a.x; t[lc + 1][rr] = (bf16)a.y;
    t[lc + 2][rr] = (bf16)a.z; t[lc + 3][rr] = (bf16)a.w;
    t[lc + 4][rr] = (bf16)b.x; t[lc + 5][rr] = (bf16)b.y;
    t[lc + 6][rr] = (bf16)b.z; t[lc + 7][rr] = (bf16)b.w;
  }
  __syncthreads();
  for (int p = 0; p < 2; ++p) {
    int rr = lr + p * 32;
    *(bf16x8*)&out[(size_t)(c0 + rr) * CC + r0 + lc] = *(const bf16x8*)&t[rr][lc];
  }
}

// ---------------- qkv fp32 -> bf16 prepass: Abf[z][row][col], 36 MB HBM (~6us)
__global__ __launch_bounds__(256)
void cvt_qkv(const float* __restrict__ qin, const float* __restrict__ kin,
             const float* __restrict__ vin, bf16* __restrict__ Abf) {
  const int z = blockIdx.y;
  const float* s = (z == 0) ? qin : (z == 1) ? kin : vin;
  size_t off = ((size_t)blockIdx.x * 256 + threadIdx.x) * 8;  // < 4194304
  float4 a = *(const float4*)(s + off);
  float4 b = *(const float4*)(s + off + 4);
  bf16x8 t;
  t[0] = (bf16)a.x; t[1] = (bf16)a.y; t[2] = (bf16)a.z; t[3] = (bf16)a.w;
  t[4] = (bf16)b.x; t[5] = (bf16)b.y; t[6] = (bf16)b.z; t[7] = (bf16)b.w;
  *(bf16x8*)&Abf[(size_t)z * ((size_t)BB * NN * CC) + off] = t;
}

// ---------------- merged QKV GEMM: 128x128 tile, BK=64 (round-8 v8 core).
// v10: BOTH packs fused. z==1 -> Kpack (round-14, verified). z==2 -> V^T
// A-frag scatter + mask row, eliminating vpack_kernel (16 MB round-trip).
// z==2 map (vs vpack's read indexing): acc[mi][ni][r] = V[key=mi*16+quad*4+r]
// [d=ni*16+l15] -> fs=ni*2+(mi>>1), lane_v=((mi&1)*2+(quad>>1))*16+l15,
// jj=(quad&1)*4+r; 4 r-values = bf16x4 store (16x8B vs old 64x2B scalar).
// Mask pre-applied (maskb ? acc : 0); mask row (fs8,9) written once per wave
// (1 wave = one (bh,tix)). z==0 folds log2(e) for attn3's raw v_exp_f32.
__global__ __launch_bounds__(256, 3)
void gemm_qkv(const bf16* __restrict__ Abf, const bf16* __restrict__ Wt,
              const float* __restrict__ pos, const int* __restrict__ mask,
              bf16* __restrict__ Qp, bf16* __restrict__ Kpack,
              bf16* __restrict__ Vpk, bf16* __restrict__ Mrow) {
  __shared__ bf16 As[128 * 64];   // 16 KB, chunks of 8: L = r*8 + (c^(r&7))
  __shared__ bf16 Bs[128 * 64];   // 16 KB, same swizzle
  const int bid = blockIdx.x;
  const int u = bid & 7, s = bid >> 3;       // s in [0,96)
  const int nblk = s >> 2;                   // 0..23
  const int m0 = (u * 4 + (s & 3)) * 128;
  const int z = nblk >> 3;
  const int n0 = (nblk & 7) * 128;
  const bf16* A = Abf + (size_t)z * ((size_t)BB * NN * CC);
  const bf16* Bt = Wt + (size_t)z * CC * CC;
  const int tid = threadIdx.x;
  const int wave = tid >> 6, lane = tid & 63;
  const int quad = lane >> 4, l15 = lane & 15;
  const int waveM = (wave >> 1) * 64, waveN = (wave & 1) * 64;
  f32x4 acc[4][4] = {};

  for (int k0 = 0; k0 < CC; k0 += 64) {
#pragma unroll
    for (int p = 0; p < 4; ++p) {   // B: 1024 bf16-chunks, async direct-to-LDS
      int ch = p * 256 + tid;
      int r = ch >> 3, c = (ch & 7) ^ (r & 7);
      gload_lds16(Bt + (size_t)(n0 + r) * CC + k0 + c * 8, &Bs[ch * 8]);
    }
#pragma unroll
    for (int p = 0; p < 4; ++p) {   // A: same proven path, bf16
      int ch = p * 256 + tid;
      int r = ch >> 3, c = (ch & 7) ^ (r & 7);
      gload_lds16(A + (size_t)(m0 + r) * CC + k0 + c * 8, &As[ch * 8]);
    }
    __syncthreads();
    bf16x8 af[4][2], bfr[4][2];
#pragma unroll
    for (int i = 0; i < 4; ++i) {
      int rA = waveM + i * 16 + l15;
      af[i][0] = *(const bf16x8*)&As[(rA * 8 + (quad ^ (rA & 7))) * 8];
      af[i][1] = *(const bf16x8*)&As[(rA * 8 + ((quad + 4) ^ (rA & 7))) * 8];
      int rB = waveN + i * 16 + l15;
      bfr[i][0] = *(const bf16x8*)&Bs[(rB * 8 + (quad ^ (rB & 7))) * 8];
      bfr[i][1] = *(const bf16x8*)&Bs[(rB * 8 + ((quad + 4) ^ (rB & 7))) * 8];
    }
#pragma unroll
    for (int mi = 0; mi < 4; ++mi)
#pragma unroll
      for (int ni = 0; ni < 4; ++ni) {
        acc[mi][ni] = __builtin_amdgcn_mfma_f32_16x16x32_bf16(
            af[mi][0], bfr[ni][0], acc[mi][ni], 0, 0, 0);
        acc[mi][ni] = __builtin_amdgcn_mfma_f32_16x16x32_bf16(
            af[mi][1], bfr[ni][1], acc[mi][ni], 0, 0, 0);
      }
    __syncthreads();
  }
  // epilogue: C/D col=lane&15, row=quad*4+reg
  const float scale = (z == 0) ? 0.125f * 1.44269504f : 1.0f;
  const int h2 = (n0 + waveN) >> 6;          // head for this wave's column group
  if (z == 2) {
    // ---- fused vpack: masked V^T A-frag scatter + mask row
    const int row0 = m0 + waveM;             // 64-aligned; wave = one (b,tix)
    const int b2 = row0 >> 11;
    const int tixl = (row0 & (NN - 1)) >> 6;
    const int j0 = tixl * 64;
    const int bh = b2 * HH + h2;
    const int* maskb = mask + b2 * KVN;
    const size_t tb = (size_t)(bh * 32 + tixl) * 512;
#pragma unroll
    for (int mi = 0; mi < 4; ++mi) {
      int kl0 = mi * 16 + quad * 4;
      int mv0 = maskb[j0 + kl0 + 0], mv1 = maskb[j0 + kl0 + 1];
      int mv2 = maskb[j0 + kl0 + 2], mv3 = maskb[j0 + kl0 + 3];
      int hf = mi >> 1;
      int lane_v = ((mi & 1) * 2 + (quad >> 1)) * 16 + l15;
      int jj0 = (quad & 1) * 4;
#pragma unroll
      for (int ni = 0; ni < 4; ++ni) {
        int fs = ni * 2 + hf;
        bf16x4 ov;
        ov[0] = mv0 ? (bf16)acc[mi][ni][0] : (bf16)0.f;
        ov[1] = mv1 ? (bf16)acc[mi][ni][1] : (bf16)0.f;
        ov[2] = mv2 ? (bf16)acc[mi][ni][2] : (bf16)0.f;
        ov[3] = mv3 ? (bf16)acc[mi][ni][3] : (bf16)0.f;
        *(bf16x4*)&Vpk[(size_t)fs * (1 << 19) + tb + lane_v * 8 + jj0] = ov;
      }
    }
#pragma unroll
    for (int hf = 0; hf < 2; ++hf) {
      bf16x8 mv;
#pragma unroll
      for (int jj = 0; jj < 8; ++jj)
        mv[jj] = (l15 == 0) ? (bf16)(float)maskb[j0 + hf * 32 + quad * 8 + jj]
                            : (bf16)0.f;
      *(bf16x8*)&Mrow[(size_t)hf * (1 << 19) + tb + lane * 8] = mv;
    }
  } else {
#pragma unroll
    for (int mi = 0; mi < 4; ++mi) {
#pragma unroll
      for (int r = 0; r < 4; ++r) {
        int m = m0 + waveM + mi * 16 + quad * 4 + r;
        int l = m & (NN - 1);
        if (z == 0) {
#pragma unroll
          for (int ni = 0; ni < 2; ++ni) {
            int col = n0 + waveN + ni * 16 + l15;
            int d = ni * 16 + l15;               // head-local, in [0,32)
            float x1 = acc[mi][ni][r], x2 = acc[mi][ni + 2][r];
            float s1, c1, s2f, c2f;
            __sincosf(pos[l * HD + d], &s1, &c1);
            __sincosf(pos[l * HD + d + 32], &s2f, &c2f);
            Qp[(size_t)m * CC + col]      = (bf16)((x1 * c1 - x2 * s1) * scale);
            Qp[(size_t)m * CC + col + 32] = (bf16)((x2 * c2f + x1 * s2f) * scale);
          }
        } else {  // z == 1: RoPE + direct Kpack scatter (round-14 verified)
          int key = l;
          int bb2 = m >> 11;
          size_t kb_ = ((((size_t)(bb2 * HH + h2)) * 32 + (key >> 6)) * 8
                        + ((key >> 4) & 3) * 2) * 512 + (size_t)(key & 15) * 8;
#pragma unroll
          for (int ni = 0; ni < 2; ++ni) {
            int d = ni * 16 + l15;               // in [0,32); pair at d+32
            float x1 = acc[mi][ni][r], x2 = acc[mi][ni + 2][r];
            float s1, c1, s2f, c2f;
            __sincosf(pos[l * HD + d], &s1, &c1);
            __sincosf(pos[l * HD + d + 32], &s2f, &c2f);
            size_t off = kb_ + ((d >> 3) & 3) * 128 + (d & 7);
            Kpack[off]       = (bf16)(x1 * c1 - x2 * s1);    // d
            Kpack[off + 512] = (bf16)(x2 * c2f + x1 * s2f);  // d+32 (hf=1)
          }
        }
      }
    }
  }
}

// ---------------- attention v7 (round-13 structure, 46-47us measured): grid
// 512, 2qc x 2kh waves, 16 iters, single parallel merge, base-2 softmax via
// raw v_exp_f32, setprio on MFMA clusters. V frags now fs0-7 from Vpk (1MB
// stride) + mask rows fs8,9 from Mrow.
__global__ __launch_bounds__(256, 2)
void attn3(const bf16* __restrict__ Qp, const bf16* __restrict__ Kpack,
           const bf16* __restrict__ Vpk, const bf16* __restrict__ Mrow,
           bf16* __restrict__ X) {
  __shared__ char smem[49152];      // [0,8K): per-wave P; [8K,48K): merge buffer
  const int tid = threadIdx.x, wave = tid >> 6, lane = tid & 63;
  const int quad = lane >> 4, l15 = lane & 15;
  const int bid = blockIdx.x;
  const int u = bid & 7, s = bid >> 3;
  const int bh = u * 4 + (s & 3), qp = s >> 2;
  const int b = bh >> 4, h = bh & 15;
  const int qc = qp * 2 + (wave >> 1), kh = wave & 1;
  const int q0 = qc * 64;
  const int sw = 2 * (l15 & 7);

  bf16* P = (bf16*)(smem + wave * 2048);
  float* mrg = (float*)(smem + 8192);

  bf16x8 qa[4][2];
#pragma unroll
  for (int g = 0; g < 4; ++g) {
    const bf16* qrow = Qp + ((size_t)(b * NN) + q0 + g * 16 + l15) * CC + h * HD;
    qa[g][0] = *(const bf16x8*)&qrow[quad * 8];
    qa[g][1] = *(const bf16x8*)&qrow[32 + quad * 8];
  }

  f32x4 Oacc[4][5] = {};
  const bf16* kbase = Kpack + (size_t)bh * 32 * 8 * 512;

  for (int it = 0; it < 16; ++it) {
    int t = kh * 16 + it;
    bf16x8 kb[8], vb[10];
#pragma unroll
    for (int fs = 0; fs < 8; ++fs)
      kb[fs] = *(const bf16x8*)&kbase[((size_t)t * 8 + fs) * 512 + lane * 8];
#pragma unroll
    for (int fs = 0; fs < 10; ++fs) {
      const bf16* vbs = (fs < 8) ? (Vpk + (size_t)fs * (1 << 19))
                                 : (Mrow + (size_t)(fs - 8) * (1 << 19));
      vb[fs] = *(const bf16x8*)&vbs[((size_t)(bh * 32 + t)) * 512 + lane * 8];
    }
#pragma unroll
    for (int g = 0; g < 4; ++g) {
      f32x4 sg[4];
      __builtin_amdgcn_s_setprio(1);
#pragma unroll
      for (int ni = 0; ni < 4; ++ni) {
        f32x4 zz = {};
        zz = __builtin_amdgcn_mfma_f32_16x16x32_bf16(kb[ni * 2], qa[g][0], zz, 0, 0, 0);
        zz = __builtin_amdgcn_mfma_f32_16x16x32_bf16(kb[ni * 2 + 1], qa[g][1], zz, 0, 0, 0);
        sg[ni] = zz;
      }
      __builtin_amdgcn_s_setprio(0);
#pragma unroll
      for (int ni = 0; ni < 4; ++ni) {
        bf16x4 pk;
#pragma unroll
        for (int r = 0; r < 4; ++r) pk[r] = (bf16)exp2_raw(sg[ni][r] - 5.7707802f);
        *(bf16x4*)&P[(l15 * 16 + ((ni * 4 + quad) ^ sw)) * 4] = pk;
      }
      bf16x8 pf0 = *(const bf16x8*)&P[(l15 * 16 + ((quad * 2) ^ sw)) * 4];
      bf16x8 pf1 = *(const bf16x8*)&P[(l15 * 16 + ((8 + quad * 2) ^ sw)) * 4];
      __builtin_amdgcn_s_setprio(1);
#pragma unroll
      for (int ni = 0; ni < 5; ++ni) {
        Oacc[g][ni] = __builtin_amdgcn_mfma_f32_16x16x32_bf16(vb[ni * 2], pf0, Oacc[g][ni], 0, 0, 0);
        Oacc[g][ni] = __builtin_amdgcn_mfma_f32_16x16x32_bf16(vb[ni * 2 + 1], pf1, Oacc[g][ni], 0, 0, 0);
      }
      __builtin_amdgcn_s_setprio(0);
    }
  }
  if (kh == 1) {
    float* dst = mrg + (wave >> 1) * 5120 + lane * 4;
#pragma unroll
    for (int g = 0; g < 4; ++g)
#pragma unroll
      for (int ni = 0; ni < 5; ++ni)
        *(f32x4*)&dst[(g * 5 + ni) * 256] = Oacc[g][ni];
  }
  __syncthreads();
  if (kh == 0) {
    float* src = mrg + (wave >> 1) * 5120 + lane * 4;
#pragma unroll
    for (int g = 0; g < 4; ++g) {
#pragma unroll
      for (int ni = 0; ni < 5; ++ni) {
        f32x4 o = *(const f32x4*)&src[(g * 5 + ni) * 256];
#pragma unroll
        for (int r = 0; r < 4; ++r) Oacc[g][ni][r] += o[r];
      }
      float ls = __shfl(Oacc[g][4][0], l15, 64);
      float rn = 1.0f / ls;
#pragma unroll
      for (int ni = 0; ni < 4; ++ni) {
        bf16x4 ov;
#pragma unroll
        for (int r = 0; r < 4; ++r) ov[r] = (bf16)(Oacc[g][ni][r] * rn);
        *(bf16x4*)&X[((size_t)(b * NN) + q0 + g * 16 + l15) * CC
                     + h * HD + ni * 16 + quad * 4] = ov;
      }
    }
  }
}

// ---------------- projection GEMM: 64x128 tile, BK=64, 8-slot swizzle, grid 512
__global__ __launch_bounds__(256, 4)
void gemm_proj(const bf16* __restrict__ A, const bf16* __restrict__ Bt,
               float* __restrict__ Out) {
  __shared__ bf16 As[64 * 64];    // 8 KB
  __shared__ bf16 Bs[128 * 64];   // 16 KB
  const int bid = blockIdx.x;
  const int u = bid & 7, s = bid >> 3;        // s in [0,64)
  const int m0 = (u * 8 + (s >> 3)) * 64;
  const int n0 = (s & 7) * 128;
  const int tid = threadIdx.x;
  const int wave = tid >> 6, lane = tid & 63;
  const int quad = lane >> 4, l15 = lane & 15;
  const int waveM = (wave >> 1) * 32, waveN = (wave & 1) * 64;
  f32x4 acc[2][4] = {};

  for (int k0 = 0; k0 < CC; k0 += 64) {
#pragma unroll
    for (int p = 0; p < 2; ++p) {
      int ch = p * 256 + tid;
      int r = ch >> 3, c = (ch & 7) ^ (r & 7);
      gload_lds16(A + (size_t)(m0 + r) * CC + k0 + c * 8, &As[ch * 8]);
    }
#pragma unroll
    for (int p = 0; p < 4; ++p) {
      int ch = p * 256 + tid;
      int r = ch >> 3, c = (ch & 7) ^ (r & 7);
      gload_lds16(Bt + (size_t)(n0 + r) * CC + k0 + c * 8, &Bs[ch * 8]);
    }
    __syncthreads();
    bf16x8 af[2][2], bfr[4][2];
#pragma unroll
    for (int i = 0; i < 2; ++i) {
      int rA = waveM + i * 16 + l15;
      af[i][0] = *(const bf16x8*)&As[(rA * 8 + (quad ^ (rA & 7))) * 8];
      af[i][1] = *(const bf16x8*)&As[(rA * 8 + ((quad + 4) ^ (rA & 7))) * 8];
    }
#pragma unroll
    for (int i = 0; i < 4; ++i) {
      int rB = waveN + i * 16 + l15;
      bfr[i][0] = *(const bf16x8*)&Bs[(rB * 8 + (quad ^ (rB & 7))) * 8];
      bfr[i][1] = *(const bf16x8*)&Bs[(rB * 8 + ((quad + 4) ^ (rB & 7))) * 8];
    }
#pragma unroll
    for (int mi = 0; mi < 2; ++mi)
#pragma unroll
      for (int ni = 0; ni < 4; ++ni) {
        acc[mi][ni] = __builtin_amdgcn_mfma_f32_16x16x32_bf16(
            af[mi][0], bfr[ni][0], acc[mi][ni], 0, 0, 0);
        acc[mi][ni] = __builtin_amdgcn_mfma_f32_16x16x32_bf16(
            af[mi][1], bfr[ni][1], acc[mi][ni], 0, 0, 0);
      }
    __syncthreads();
  }
#pragma unroll
  for (int mi = 0; mi < 2; ++mi)
#pragma unroll
    for (int ni = 0; ni < 4; ++ni)
#pragma unroll
      for (int r = 0; r < 4; ++r) {
        int row = m0 + waveM + mi * 16 + quad * 4 + r;
        int col = n0 + waveN + ni * 16 + l15;
        Out[(size_t)row * CC + col] = acc[mi][ni][r];
      }
}

extern "C" void kernel_launch(void* const* d_in, const int* in_sizes, int n_in,
                              void* d_out, int out_size, void* d_ws, size_t ws_size,
                              hipStream_t stream) {
  const float* q    = (const float*)d_in[0];
  const float* k    = (const float*)d_in[1];
  const float* v    = (const float*)d_in[2];
  const int*   mask = (const int*)d_in[3];
  const float* pos  = (const float*)d_in[4];
  const float* qW   = (const float*)d_in[5];
  const float* kW   = (const float*)d_in[6];
  const float* vW   = (const float*)d_in[7];
  const float* pW   = (const float*)d_in[8];
  float* out = (float*)d_out;

  char* w = (char*)d_ws;
  const size_t MB = 1024 * 1024;
  // layout (58MB peak; 56MB footprint proven rounds 8-14):
  //   Wt@0-8     (pWt@6-8 live to gemm_proj)
  //   Qp@8-16    (gemm_qkv -> attn3)
  //   Kpack@16-24 (gemm_qkv z==1 -> attn3)
  //   Vpk@24-32  (gemm_qkv z==2 -> attn3; V^T frags fs0-7, 1MB stride)
  //   Abf@32-56  (cvt_qkv -> gemm_qkv, 24MB, dead after)
  //   Mrow@56-58 (gemm_qkv z==2 -> attn3; mask rows fs8,9)
  //   X@32-40    over dead Abf head (attn3 -> gemm_proj)
  bf16* Wt    = (bf16*)(w);
  bf16* Qp    = (bf16*)(w + 8 * MB);
  bf16* Kpack = (bf16*)(w + 16 * MB);
  bf16* Vpk   = (bf16*)(w + 24 * MB);
  bf16* Abf   = (bf16*)(w + 32 * MB);
  bf16* Mrow  = (bf16*)(w + 56 * MB);
  bf16* X     = (bf16*)(w + 32 * MB);

  wtrans<<<dim3(16, 16, 4), 256, 0, stream>>>(qW, kW, vW, pW, Wt);
  cvt_qkv<<<dim3(2048, 3), 256, 0, stream>>>(q, k, v, Abf);
  gemm_qkv<<<dim3(768), 256, 0, stream>>>(Abf, Wt, pos, mask, Qp, Kpack, Vpk, Mrow);
  attn3<<<dim3(512), 256, 0, stream>>>(Qp, Kpack, Vpk, Mrow, X);
  gemm_proj<<<dim3(512), 256, 0, stream>>>(X, Wt + 3 * (size_t)CC * CC, out);
}

// Round 16
// 198.159 us; speedup vs baseline: 1.1008x; 1.0522x over previous
//
#include <hip/hip_runtime.h>
#include <hip/hip_bf16.h>

#define BB 2
#define NN 2048
#define KVN 2048
#define CC 1024
#define HH 16
#define HD 64

typedef __bf16 bf16;
typedef __attribute__((ext_vector_type(4))) __bf16 bf16x4;
typedef __attribute__((ext_vector_type(8))) __bf16 bf16x8;
typedef __attribute__((ext_vector_type(4))) float f32x4;

__device__ __forceinline__ void gload_lds16(const void* g, void* l) {
  __builtin_amdgcn_global_load_lds(
      (const __attribute__((address_space(1))) void*)g,
      (__attribute__((address_space(3))) void*)l, 16, 0, 0);
}

__device__ __forceinline__ float exp2_raw(float x) {
  float r;
  asm("v_exp_f32 %0, %1" : "=v"(r) : "v"(x));   // D = 2^S0, 1 VALU op
  return r;
}

// ---------------- batched weight transpose: Wt[z][c][r] = (bf16)W_z[r][c]
__global__ __launch_bounds__(256)
void wtrans(const float* __restrict__ qW, const float* __restrict__ kW,
            const float* __restrict__ vW, const float* __restrict__ pW,
            bf16* __restrict__ Wt) {
  __shared__ bf16 t[64][72];
  const float* in = (blockIdx.z == 0) ? qW : (blockIdx.z == 1) ? kW
                    : (blockIdx.z == 2) ? vW : pW;
  bf16* out = Wt + (size_t)blockIdx.z * CC * CC;
  int r0 = blockIdx.y * 64, c0 = blockIdx.x * 64;
  int tid = threadIdx.x;
  int lr = tid >> 3, lc = (tid & 7) * 8;
  for (int p = 0; p < 2; ++p) {
    int rr = lr + p * 32;
    const float* src = &in[(size_t)(r0 + rr) * CC + c0 + lc];
    float4 a = *(const float4*)src;
    float4 b = *(const float4*)(src + 4);
    t[lc + 0][rr] = (bf16)a.x; t[lc + 1][rr] = (bf16)a.y;
    t[lc + 2][rr] = (bf16)a.z; t[lc + 3][rr] = (bf16)a.w;
    t[lc + 4][rr] = (bf16)b.x; t[lc + 5][rr] = (bf16)b.y;
    t[lc + 6][rr] = (bf16)b.z; t[lc + 7][rr] = (bf16)b.w;
  }
  __syncthreads();
  for (int p = 0; p < 2; ++p) {
    int rr = lr + p * 32;
    *(bf16x8*)&out[(size_t)(c0 + rr) * CC + r0 + lc] = *(const bf16x8*)&t[rr][lc];
  }
}

// ---------------- qkv fp32 -> bf16 prepass: Abf[z][row][col], 36 MB HBM (~6us)
__global__ __launch_bounds__(256)
void cvt_qkv(const float* __restrict__ qin, const float* __restrict__ kin,
             const float* __restrict__ vin, bf16* __restrict__ Abf) {
  const int z = blockIdx.y;
  const float* s = (z == 0) ? qin : (z == 1) ? kin : vin;
  size_t off = ((size_t)blockIdx.x * 256 + threadIdx.x) * 8;  // < 4194304
  float4 a = *(const float4*)(s + off);
  float4 b = *(const float4*)(s + off + 4);
  bf16x8 t;
  t[0] = (bf16)a.x; t[1] = (bf16)a.y; t[2] = (bf16)a.z; t[3] = (bf16)a.w;
  t[4] = (bf16)b.x; t[5] = (bf16)b.y; t[6] = (bf16)b.z; t[7] = (bf16)b.w;
  *(bf16x8*)&Abf[(size_t)z * ((size_t)BB * NN * CC) + off] = t;
}

// ---------------- RoPE cos/sin table: tab[l*HD+d] = (cos,sin)(pos[l][d]).
// 131072 float2 = 1 MB, L2-resident; kills the 64 sincosf/thread in
// gemm_qkv's epilogue (trans ops are quarter-rate; G13/App-B RoPE guidance).
__global__ __launch_bounds__(256)
void postab(const float* __restrict__ pos, float2* __restrict__ tab) {
  int i = blockIdx.x * 256 + threadIdx.x;   // grid 512 -> 131072
  float p = pos[i];
  float s, c;
  __sincosf(p, &s, &c);
  tab[i] = make_float2(c, s);
}

// ---------------- merged QKV GEMM: 128x128 tile, BK=64 (round-8 v8 core).
// v11: both packs fused (rounds 14/15, verified) + RoPE via precomputed
// cos/sin table (same loads as before -- tab[l*HD+d] replaces pos[l*HD+d] --
// but zero transcendentals in the epilogue). z==0 folds log2(e) into scale.
__global__ __launch_bounds__(256, 3)
void gemm_qkv(const bf16* __restrict__ Abf, const bf16* __restrict__ Wt,
              const float2* __restrict__ tab, const int* __restrict__ mask,
              bf16* __restrict__ Qp, bf16* __restrict__ Kpack,
              bf16* __restrict__ Vpk, bf16* __restrict__ Mrow) {
  __shared__ bf16 As[128 * 64];   // 16 KB, chunks of 8: L = r*8 + (c^(r&7))
  __shared__ bf16 Bs[128 * 64];   // 16 KB, same swizzle
  const int bid = blockIdx.x;
  const int u = bid & 7, s = bid >> 3;       // s in [0,96)
  const int nblk = s >> 2;                   // 0..23
  const int m0 = (u * 4 + (s & 3)) * 128;
  const int z = nblk >> 3;
  const int n0 = (nblk & 7) * 128;
  const bf16* A = Abf + (size_t)z * ((size_t)BB * NN * CC);
  const bf16* Bt = Wt + (size_t)z * CC * CC;
  const int tid = threadIdx.x;
  const int wave = tid >> 6, lane = tid & 63;
  const int quad = lane >> 4, l15 = lane & 15;
  const int waveM = (wave >> 1) * 64, waveN = (wave & 1) * 64;
  f32x4 acc[4][4] = {};

  for (int k0 = 0; k0 < CC; k0 += 64) {
#pragma unroll
    for (int p = 0; p < 4; ++p) {   // B: 1024 bf16-chunks, async direct-to-LDS
      int ch = p * 256 + tid;
      int r = ch >> 3, c = (ch & 7) ^ (r & 7);
      gload_lds16(Bt + (size_t)(n0 + r) * CC + k0 + c * 8, &Bs[ch * 8]);
    }
#pragma unroll
    for (int p = 0; p < 4; ++p) {   // A: same proven path, bf16
      int ch = p * 256 + tid;
      int r = ch >> 3, c = (ch & 7) ^ (r & 7);
      gload_lds16(A + (size_t)(m0 + r) * CC + k0 + c * 8, &As[ch * 8]);
    }
    __syncthreads();
    bf16x8 af[4][2], bfr[4][2];
#pragma unroll
    for (int i = 0; i < 4; ++i) {
      int rA = waveM + i * 16 + l15;
      af[i][0] = *(const bf16x8*)&As[(rA * 8 + (quad ^ (rA & 7))) * 8];
      af[i][1] = *(const bf16x8*)&As[(rA * 8 + ((quad + 4) ^ (rA & 7))) * 8];
      int rB = waveN + i * 16 + l15;
      bfr[i][0] = *(const bf16x8*)&Bs[(rB * 8 + (quad ^ (rB & 7))) * 8];
      bfr[i][1] = *(const bf16x8*)&Bs[(rB * 8 + ((quad + 4) ^ (rB & 7))) * 8];
    }
#pragma unroll
    for (int mi = 0; mi < 4; ++mi)
#pragma unroll
      for (int ni = 0; ni < 4; ++ni) {
        acc[mi][ni] = __builtin_amdgcn_mfma_f32_16x16x32_bf16(
            af[mi][0], bfr[ni][0], acc[mi][ni], 0, 0, 0);
        acc[mi][ni] = __builtin_amdgcn_mfma_f32_16x16x32_bf16(
            af[mi][1], bfr[ni][1], acc[mi][ni], 0, 0, 0);
      }
    __syncthreads();
  }
  // epilogue: C/D col=lane&15, row=quad*4+reg
  const float scale = (z == 0) ? 0.125f * 1.44269504f : 1.0f;
  const int h2 = (n0 + waveN) >> 6;          // head for this wave's column group
  if (z == 2) {
    // ---- fused vpack: masked V^T A-frag scatter + mask row (round-15)
    const int row0 = m0 + waveM;             // 64-aligned; wave = one (b,tix)
    const int b2 = row0 >> 11;
    const int tixl = (row0 & (NN - 1)) >> 6;
    const int j0 = tixl * 64;
    const int bh = b2 * HH + h2;
    const int* maskb = mask + b2 * KVN;
    const size_t tb = (size_t)(bh * 32 + tixl) * 512;
#pragma unroll
    for (int mi = 0; mi < 4; ++mi) {
      int kl0 = mi * 16 + quad * 4;
      int mv0 = maskb[j0 + kl0 + 0], mv1 = maskb[j0 + kl0 + 1];
      int mv2 = maskb[j0 + kl0 + 2], mv3 = maskb[j0 + kl0 + 3];
      int hf = mi >> 1;
      int lane_v = ((mi & 1) * 2 + (quad >> 1)) * 16 + l15;
      int jj0 = (quad & 1) * 4;
#pragma unroll
      for (int ni = 0; ni < 4; ++ni) {
        int fs = ni * 2 + hf;
        bf16x4 ov;
        ov[0] = mv0 ? (bf16)acc[mi][ni][0] : (bf16)0.f;
        ov[1] = mv1 ? (bf16)acc[mi][ni][1] : (bf16)0.f;
        ov[2] = mv2 ? (bf16)acc[mi][ni][2] : (bf16)0.f;
        ov[3] = mv3 ? (bf16)acc[mi][ni][3] : (bf16)0.f;
        *(bf16x4*)&Vpk[(size_t)fs * (1 << 19) + tb + lane_v * 8 + jj0] = ov;
      }
    }
#pragma unroll
    for (int hf = 0; hf < 2; ++hf) {
      bf16x8 mv;
#pragma unroll
      for (int jj = 0; jj < 8; ++jj)
        mv[jj] = (l15 == 0) ? (bf16)(float)maskb[j0 + hf * 32 + quad * 8 + jj]
                            : (bf16)0.f;
      *(bf16x8*)&Mrow[(size_t)hf * (1 << 19) + tb + lane * 8] = mv;
    }
  } else {
#pragma unroll
    for (int mi = 0; mi < 4; ++mi) {
#pragma unroll
      for (int r = 0; r < 4; ++r) {
        int m = m0 + waveM + mi * 16 + quad * 4 + r;
        int l = m & (NN - 1);
        if (z == 0) {
#pragma unroll
          for (int ni = 0; ni < 2; ++ni) {
            int col = n0 + waveN + ni * 16 + l15;
            int d = ni * 16 + l15;               // head-local, in [0,32)
            float x1 = acc[mi][ni][r], x2 = acc[mi][ni + 2][r];
            float2 cs1 = tab[l * HD + d];
            float2 cs2 = tab[l * HD + d + 32];
            Qp[(size_t)m * CC + col]      = (bf16)((x1 * cs1.x - x2 * cs1.y) * scale);
            Qp[(size_t)m * CC + col + 32] = (bf16)((x2 * cs2.x + x1 * cs2.y) * scale);
          }
        } else {  // z == 1: RoPE + direct Kpack scatter (round-14 verified)
          int key = l;
          int bb2 = m >> 11;
          size_t kb_ = ((((size_t)(bb2 * HH + h2)) * 32 + (key >> 6)) * 8
                        + ((key >> 4) & 3) * 2) * 512 + (size_t)(key & 15) * 8;
#pragma unroll
          for (int ni = 0; ni < 2; ++ni) {
            int d = ni * 16 + l15;               // in [0,32); pair at d+32
            float x1 = acc[mi][ni][r], x2 = acc[mi][ni + 2][r];
            float2 cs1 = tab[l * HD + d];
            float2 cs2 = tab[l * HD + d + 32];
            size_t off = kb_ + ((d >> 3) & 3) * 128 + (d & 7);
            Kpack[off]       = (bf16)(x1 * cs1.x - x2 * cs1.y);    // d
            Kpack[off + 512] = (bf16)(x2 * cs2.x + x1 * cs2.y);    // d+32
          }
        }
      }
    }
  }
}

// ---------------- attention v7 (round-13 structure, 45.5-46.5us measured):
// grid 512, 2qc x 2kh waves, 16 iters, single parallel merge, base-2 softmax
// via raw v_exp_f32, setprio on MFMA clusters. V frags fs0-7 from Vpk (1MB
// stride) + mask rows fs8,9 from Mrow.
__global__ __launch_bounds__(256, 2)
void attn3(const bf16* __restrict__ Qp, const bf16* __restrict__ Kpack,
           const bf16* __restrict__ Vpk, const bf16* __restrict__ Mrow,
           bf16* __restrict__ X) {
  __shared__ char smem[49152];      // [0,8K): per-wave P; [8K,48K): merge buffer
  const int tid = threadIdx.x, wave = tid >> 6, lane = tid & 63;
  const int quad = lane >> 4, l15 = lane & 15;
  const int bid = blockIdx.x;
  const int u = bid & 7, s = bid >> 3;
  const int bh = u * 4 + (s & 3), qp = s >> 2;
  const int b = bh >> 4, h = bh & 15;
  const int qc = qp * 2 + (wave >> 1), kh = wave & 1;
  const int q0 = qc * 64;
  const int sw = 2 * (l15 & 7);

  bf16* P = (bf16*)(smem + wave * 2048);
  float* mrg = (float*)(smem + 8192);

  bf16x8 qa[4][2];
#pragma unroll
  for (int g = 0; g < 4; ++g) {
    const bf16* qrow = Qp + ((size_t)(b * NN) + q0 + g * 16 + l15) * CC + h * HD;
    qa[g][0] = *(const bf16x8*)&qrow[quad * 8];
    qa[g][1] = *(const bf16x8*)&qrow[32 + quad * 8];
  }

  f32x4 Oacc[4][5] = {};
  const bf16* kbase = Kpack + (size_t)bh * 32 * 8 * 512;

  for (int it = 0; it < 16; ++it) {
    int t = kh * 16 + it;
    bf16x8 kb[8], vb[10];
#pragma unroll
    for (int fs = 0; fs < 8; ++fs)
      kb[fs] = *(const bf16x8*)&kbase[((size_t)t * 8 + fs) * 512 + lane * 8];
#pragma unroll
    for (int fs = 0; fs < 10; ++fs) {
      const bf16* vbs = (fs < 8) ? (Vpk + (size_t)fs * (1 << 19))
                                 : (Mrow + (size_t)(fs - 8) * (1 << 19));
      vb[fs] = *(const bf16x8*)&vbs[((size_t)(bh * 32 + t)) * 512 + lane * 8];
    }
#pragma unroll
    for (int g = 0; g < 4; ++g) {
      f32x4 sg[4];
      __builtin_amdgcn_s_setprio(1);
#pragma unroll
      for (int ni = 0; ni < 4; ++ni) {
        f32x4 zz = {};
        zz = __builtin_amdgcn_mfma_f32_16x16x32_bf16(kb[ni * 2], qa[g][0], zz, 0, 0, 0);
        zz = __builtin_amdgcn_mfma_f32_16x16x32_bf16(kb[ni * 2 + 1], qa[g][1], zz, 0, 0, 0);
        sg[ni] = zz;
      }
      __builtin_amdgcn_s_setprio(0);
#pragma unroll
      for (int ni = 0; ni < 4; ++ni) {
        bf16x4 pk;
#pragma unroll
        for (int r = 0; r < 4; ++r) pk[r] = (bf16)exp2_raw(sg[ni][r] - 5.7707802f);
        *(bf16x4*)&P[(l15 * 16 + ((ni * 4 + quad) ^ sw)) * 4] = pk;
      }
      bf16x8 pf0 = *(const bf16x8*)&P[(l15 * 16 + ((quad * 2) ^ sw)) * 4];
      bf16x8 pf1 = *(const bf16x8*)&P[(l15 * 16 + ((8 + quad * 2) ^ sw)) * 4];
      __builtin_amdgcn_s_setprio(1);
#pragma unroll
      for (int ni = 0; ni < 5; ++ni) {
        Oacc[g][ni] = __builtin_amdgcn_mfma_f32_16x16x32_bf16(vb[ni * 2], pf0, Oacc[g][ni], 0, 0, 0);
        Oacc[g][ni] = __builtin_amdgcn_mfma_f32_16x16x32_bf16(vb[ni * 2 + 1], pf1, Oacc[g][ni], 0, 0, 0);
      }
      __builtin_amdgcn_s_setprio(0);
    }
  }
  if (kh == 1) {
    float* dst = mrg + (wave >> 1) * 5120 + lane * 4;
#pragma unroll
    for (int g = 0; g < 4; ++g)
#pragma unroll
      for (int ni = 0; ni < 5; ++ni)
        *(f32x4*)&dst[(g * 5 + ni) * 256] = Oacc[g][ni];
  }
  __syncthreads();
  if (kh == 0) {
    float* src = mrg + (wave >> 1) * 5120 + lane * 4;
#pragma unroll
    for (int g = 0; g < 4; ++g) {
#pragma unroll
      for (int ni = 0; ni < 5; ++ni) {
        f32x4 o = *(const f32x4*)&src[(g * 5 + ni) * 256];
#pragma unroll
        for (int r = 0; r < 4; ++r) Oacc[g][ni][r] += o[r];
      }
      float ls = __shfl(Oacc[g][4][0], l15, 64);
      float rn = 1.0f / ls;
#pragma unroll
      for (int ni = 0; ni < 4; ++ni) {
        bf16x4 ov;
#pragma unroll
        for (int r = 0; r < 4; ++r) ov[r] = (bf16)(Oacc[g][ni][r] * rn);
        *(bf16x4*)&X[((size_t)(b * NN) + q0 + g * 16 + l15) * CC
                     + h * HD + ni * 16 + quad * 4] = ov;
      }
    }
  }
}

// ---------------- projection GEMM: 64x128 tile, BK=64, 8-slot swizzle, grid 512
__global__ __launch_bounds__(256, 4)
void gemm_proj(const bf16* __restrict__ A, const bf16* __restrict__ Bt,
               float* __restrict__ Out) {
  __shared__ bf16 As[64 * 64];    // 8 KB
  __shared__ bf16 Bs[128 * 64];   // 16 KB
  const int bid = blockIdx.x;
  const int u = bid & 7, s = bid >> 3;        // s in [0,64)
  const int m0 = (u * 8 + (s >> 3)) * 64;
  const int n0 = (s & 7) * 128;
  const int tid = threadIdx.x;
  const int wave = tid >> 6, lane = tid & 63;
  const int quad = lane >> 4, l15 = lane & 15;
  const int waveM = (wave >> 1) * 32, waveN = (wave & 1) * 64;
  f32x4 acc[2][4] = {};

  for (int k0 = 0; k0 < CC; k0 += 64) {
#pragma unroll
    for (int p = 0; p < 2; ++p) {
      int ch = p * 256 + tid;
      int r = ch >> 3, c = (ch & 7) ^ (r & 7);
      gload_lds16(A + (size_t)(m0 + r) * CC + k0 + c * 8, &As[ch * 8]);
    }
#pragma unroll
    for (int p = 0; p < 4; ++p) {
      int ch = p * 256 + tid;
      int r = ch >> 3, c = (ch & 7) ^ (r & 7);
      gload_lds16(Bt + (size_t)(n0 + r) * CC + k0 + c * 8, &Bs[ch * 8]);
    }
    __syncthreads();
    bf16x8 af[2][2], bfr[4][2];
#pragma unroll
    for (int i = 0; i < 2; ++i) {
      int rA = waveM + i * 16 + l15;
      af[i][0] = *(const bf16x8*)&As[(rA * 8 + (quad ^ (rA & 7))) * 8];
      af[i][1] = *(const bf16x8*)&As[(rA * 8 + ((quad + 4) ^ (rA & 7))) * 8];
    }
#pragma unroll
    for (int i = 0; i < 4; ++i) {
      int rB = waveN + i * 16 + l15;
      bfr[i][0] = *(const bf16x8*)&Bs[(rB * 8 + (quad ^ (rB & 7))) * 8];
      bfr[i][1] = *(const bf16x8*)&Bs[(rB * 8 + ((quad + 4) ^ (rB & 7))) * 8];
    }
#pragma unroll
    for (int mi = 0; mi < 2; ++mi)
#pragma unroll
      for (int ni = 0; ni < 4; ++ni) {
        acc[mi][ni] = __builtin_amdgcn_mfma_f32_16x16x32_bf16(
            af[mi][0], bfr[ni][0], acc[mi][ni], 0, 0, 0);
        acc[mi][ni] = __builtin_amdgcn_mfma_f32_16x16x32_bf16(
            af[mi][1], bfr[ni][1], acc[mi][ni], 0, 0, 0);
      }
    __syncthreads();
  }
#pragma unroll
  for (int mi = 0; mi < 2; ++mi)
#pragma unroll
    for (int ni = 0; ni < 4; ++ni)
#pragma unroll
      for (int r = 0; r < 4; ++r) {
        int row = m0 + waveM + mi * 16 + quad * 4 + r;
        int col = n0 + waveN + ni * 16 + l15;
        Out[(size_t)row * CC + col] = acc[mi][ni][r];
      }
}

extern "C" void kernel_launch(void* const* d_in, const int* in_sizes, int n_in,
                              void* d_out, int out_size, void* d_ws, size_t ws_size,
                              hipStream_t stream) {
  const float* q    = (const float*)d_in[0];
  const float* k    = (const float*)d_in[1];
  const float* v    = (const float*)d_in[2];
  const int*   mask = (const int*)d_in[3];
  const float* pos  = (const float*)d_in[4];
  const float* qW   = (const float*)d_in[5];
  const float* kW   = (const float*)d_in[6];
  const float* vW   = (const float*)d_in[7];
  const float* pW   = (const float*)d_in[8];
  float* out = (float*)d_out;

  char* w = (char*)d_ws;
  const size_t MB = 1024 * 1024;
  // layout (59MB peak; 58MB proven round 15):
  //   Wt@0-8     (pWt@6-8 live to gemm_proj)
  //   Qp@8-16    (gemm_qkv -> attn3)
  //   Kpack@16-24 (gemm_qkv z==1 -> attn3)
  //   Vpk@24-32  (gemm_qkv z==2 -> attn3; V^T frags fs0-7, 1MB stride)
  //   Abf@32-56  (cvt_qkv -> gemm_qkv, dead after)
  //   Mrow@56-58 (gemm_qkv z==2 -> attn3; mask rows fs8,9)
  //   Ptab@58-59 (postab -> gemm_qkv; RoPE cos/sin float2 table)
  //   X@32-40    over dead Abf head (attn3 -> gemm_proj)
  bf16*   Wt    = (bf16*)(w);
  bf16*   Qp    = (bf16*)(w + 8 * MB);
  bf16*   Kpack = (bf16*)(w + 16 * MB);
  bf16*   Vpk   = (bf16*)(w + 24 * MB);
  bf16*   Abf   = (bf16*)(w + 32 * MB);
  bf16*   Mrow  = (bf16*)(w + 56 * MB);
  float2* Ptab  = (float2*)(w + 58 * MB);
  bf16*   X     = (bf16*)(w + 32 * MB);

  wtrans<<<dim3(16, 16, 4), 256, 0, stream>>>(qW, kW, vW, pW, Wt);
  postab<<<dim3(512), 256, 0, stream>>>(pos, Ptab);
  cvt_qkv<<<dim3(2048, 3), 256, 0, stream>>>(q, k, v, Abf);
  gemm_qkv<<<dim3(768), 256, 0, stream>>>(Abf, Wt, Ptab, mask, Qp, Kpack, Vpk, Mrow);
  attn3<<<dim3(512), 256, 0, stream>>>(Qp, Kpack, Vpk, Mrow, X);
  gemm_proj<<<dim3(512), 256, 0, stream>>>(X, Wt + 3 * (size_t)CC * CC, out);
}